// Round 1
// baseline (69.253 us; speedup 1.0000x reference)
//
#include <hip/hip_runtime.h>

// Problem constants (from reference): inputs (8, 512, 96, 2) f32, WIN=10.
constexpr int WIN = 10;
constexpr int Bn  = 8;
constexpr int Sn  = 512;
constexpr int An  = 96;
constexpr int Vn  = 2;
constexpr int Tn  = Sn - 1;      // 511 output time steps
constexpr int AV  = An * Vn;     // 192

// Kernel 1: per-(b,a,v) mean over the full S axis. 1536 outputs, trivial.
__global__ void mean_kernel(const float* __restrict__ in, float* __restrict__ mean) {
    int idx = blockIdx.x * blockDim.x + threadIdx.x;
    if (idx >= Bn * AV) return;
    int b  = idx / AV;
    int av = idx - b * AV;
    const float* p = in + (size_t)b * Sn * AV + av;
    float acc = 0.f;
    #pragma unroll 8
    for (int s = 0; s < Sn; ++s) acc += p[(size_t)s * AV];
    mean[idx] = acc * (1.0f / Sn);
}

// Kernel 2: one block per (b, t). Stage centered window in LDS, compute
// rs = rsqrt(diag), then each thread computes a 12x3 (i,j) register tile.
__global__ __launch_bounds__(256)
void corr_kernel(const float* __restrict__ in, const float* __restrict__ mean,
                 float* __restrict__ out) {
    __shared__ float xw[WIN * AV];   // up to 10 x 96 x 2 centered values (7.5 KB)
    __shared__ float rs[An];         // rsqrt of windowed diagonal

    const int bid = blockIdx.x;
    const int b   = bid / Tn;
    const int t   = bid - b * Tn;
    int s0 = t - (WIN - 1); if (s0 < 0) s0 = 0;
    const int cnt = t - s0 + 1;      // window length, 1..10 (uniform per block)

    const int tid = threadIdx.x;

    // --- stage window into LDS, subtracting the per-(b,a,v) mean ---
    const float* src = in + ((size_t)b * Sn + s0) * AV;
    const float* mb  = mean + b * AV;
    const int tot = cnt * AV;
    for (int idx = tid; idx < tot; idx += 256) {
        int av = idx % AV;
        xw[idx] = src[idx] - mb[av];
    }
    __syncthreads();

    // --- windowed diagonal -> rsqrt ---
    if (tid < An) {
        float d = 0.f;
        for (int s = 0; s < cnt; ++s) {
            float x0 = xw[s * AV + tid * 2];
            float x1 = xw[s * AV + tid * 2 + 1];
            d += x0 * x0 + x1 * x1;
        }
        rs[tid] = rsqrtf(d);
    }
    __syncthreads();

    // --- 12x3 register tile per thread: i = ty + 8r, j = tx + 32c ---
    const int tx = tid & 31;
    const int ty = tid >> 5;

    float acc[12][3];
    #pragma unroll
    for (int r = 0; r < 12; ++r)
        #pragma unroll
        for (int c = 0; c < 3; ++c) acc[r][c] = 0.f;

    for (int s = 0; s < cnt; ++s) {
        const float* xs = &xw[s * AV];
        float2 xj[3];
        #pragma unroll
        for (int c = 0; c < 3; ++c)
            xj[c] = *reinterpret_cast<const float2*>(&xs[(tx + 32 * c) * 2]);
        #pragma unroll
        for (int r = 0; r < 12; ++r) {
            float2 xi = *reinterpret_cast<const float2*>(&xs[(ty + 8 * r) * 2]);
            #pragma unroll
            for (int c = 0; c < 3; ++c)
                acc[r][c] += xi.x * xj[c].x + xi.y * xj[c].y;
        }
    }

    // --- normalize, mask diagonal, store (coalesced 128B segments per row) ---
    float rj[3];
    #pragma unroll
    for (int c = 0; c < 3; ++c) rj[c] = rs[tx + 32 * c];

    float* ob = out + (size_t)(b * Tn + t) * An * An;
    #pragma unroll
    for (int r = 0; r < 12; ++r) {
        int i = ty + 8 * r;
        float ri = rs[i];
        #pragma unroll
        for (int c = 0; c < 3; ++c) {
            int j = tx + 32 * c;
            float v = (i == j) ? 0.f : acc[r][c] * ri * rj[c];
            ob[(size_t)i * An + j] = v;
        }
    }
}

extern "C" void kernel_launch(void* const* d_in, const int* in_sizes, int n_in,
                              void* d_out, int out_size, void* d_ws, size_t ws_size,
                              hipStream_t stream) {
    const float* in  = (const float*)d_in[0];
    float* out  = (float*)d_out;
    float* mean = (float*)d_ws;   // 1536 floats of scratch

    mean_kernel<<<(Bn * AV + 255) / 256, 256, 0, stream>>>(in, mean);
    corr_kernel<<<Bn * Tn, 256, 0, stream>>>(in, mean, out);
}

// Round 2
// 42.247 us; speedup vs baseline: 1.6392x; 1.6392x over previous
//
#include <hip/hip_runtime.h>

// inputs (8, 512, 96, 2) f32, WIN=10. Output (8, 511, 96, 96) f32 = 150.7 MB.
constexpr int WIN = 10;
constexpr int Bn  = 8;
constexpr int Sn  = 512;
constexpr int An  = 96;
constexpr int Vn  = 2;
constexpr int Tn  = Sn - 1;        // 511 output time steps
constexpr int AV  = An * Vn;       // 192

constexpr int SCHUNK = 32;         // s-rows per partial-sum block
constexpr int NCH    = Sn / SCHUNK; // 16
constexpr int CH     = 8;          // t-outputs per corr block
constexpr int CHUNKS_PER_B = (Tn + CH - 1) / CH;  // 64
constexpr int MAXROWS = CH + WIN - 1;             // 17 staged s-rows

// ---- mean pass, stage 1: partial sums over 32-s chunks (coalesced) ----
__global__ __launch_bounds__(192)
void partial_kernel(const float* __restrict__ in, float* __restrict__ partial) {
    const int blk = blockIdx.x;             // b * NCH + c
    const int b   = blk / NCH;
    const int c   = blk - b * NCH;
    const int av  = threadIdx.x;            // 0..191, coalesced across wave
    const float* p = in + ((size_t)(b * Sn + c * SCHUNK)) * AV + av;
    float acc = 0.f;
    #pragma unroll
    for (int s = 0; s < SCHUNK; ++s) acc += p[(size_t)s * AV];
    partial[(size_t)blk * AV + av] = acc;
}

// ---- mean pass, stage 2: reduce 16 partials -> per-(b,av) sum ----
__global__ __launch_bounds__(256)
void reduce_kernel(const float* __restrict__ partial, float* __restrict__ sums) {
    int idx = blockIdx.x * blockDim.x + threadIdx.x;
    if (idx >= Bn * AV) return;
    int b  = idx / AV;
    int av = idx - b * AV;
    float acc = 0.f;
    #pragma unroll
    for (int c = 0; c < NCH; ++c) acc += partial[(size_t)(b * NCH + c) * AV + av];
    sums[idx] = acc;   // sum, not mean; corr scales by 1/Sn
}

// ---- corr: one block per (b, 8-t chunk); sliding-window rank-2 updates ----
__global__ __launch_bounds__(256)
void corr_kernel(const float* __restrict__ in, const float* __restrict__ sums,
                 float* __restrict__ out) {
    __shared__ float xw[MAXROWS * AV];   // centered rows, 17*192*4 = 12.75 KB

    const int bid   = blockIdx.x;
    const int b     = bid / CHUNKS_PER_B;
    const int chunk = bid - b * CHUNKS_PER_B;
    const int t0    = chunk * CH;
    const int t1    = min(t0 + CH - 1, Tn - 1);
    int sbase = t0 - (WIN - 1); if (sbase < 0) sbase = 0;
    const int nrows = t1 - sbase + 1;    // <= 17

    const int tid = threadIdx.x;

    // --- stage rows [sbase..t1], centered, float2-vectorized ---
    {
        const float2* src = reinterpret_cast<const float2*>(
            in + ((size_t)(b * Sn + sbase)) * AV);
        const float2* mb = reinterpret_cast<const float2*>(sums + b * AV);
        float2* dst = reinterpret_cast<float2*>(xw);
        const int tot2 = nrows * (AV / 2);
        constexpr float invS = 1.0f / Sn;
        for (int idx = tid; idx < tot2; idx += 256) {
            int av2 = idx % (AV / 2);
            float2 v = src[idx], m = mb[av2];
            dst[idx] = make_float2(v.x - m.x * invS, v.y - m.y * invS);
        }
    }
    __syncthreads();

    const int tx = tid & 31;   // j = tx + 32c
    const int ty = tid >> 5;   // i = ty + 8r

    float acc[12][3];
    float di[12], dj[3];
    #pragma unroll
    for (int r = 0; r < 12; ++r) {
        di[r] = 0.f;
        #pragma unroll
        for (int c = 0; c < 3; ++c) acc[r][c] = 0.f;
    }
    #pragma unroll
    for (int c = 0; c < 3; ++c) dj[c] = 0.f;

    // rank-2 (V=2) accumulate of row `ls` with sign `sgn`
    auto accum = [&](int ls, float sgn) {
        const float* xs = &xw[ls * AV];
        float2 xj[3];
        #pragma unroll
        for (int c = 0; c < 3; ++c) {
            xj[c] = *reinterpret_cast<const float2*>(&xs[(tx + 32 * c) * 2]);
            dj[c] += sgn * (xj[c].x * xj[c].x + xj[c].y * xj[c].y);
        }
        #pragma unroll
        for (int r = 0; r < 12; ++r) {
            float2 x = *reinterpret_cast<const float2*>(&xs[(ty + 8 * r) * 2]);
            float2 xs2 = make_float2(sgn * x.x, sgn * x.y);
            di[r] += xs2.x * x.x + xs2.y * x.y;
            #pragma unroll
            for (int c = 0; c < 3; ++c)
                acc[r][c] += xs2.x * xj[c].x + xs2.y * xj[c].y;
        }
    };

    // normalize + mask + store one t
    auto emit = [&](int t) {
        float rsj[3];
        #pragma unroll
        for (int c = 0; c < 3; ++c) rsj[c] = rsqrtf(dj[c]);
        float* ob = out + (size_t)(b * Tn + t) * (An * An);
        #pragma unroll
        for (int r = 0; r < 12; ++r) {
            int i = ty + 8 * r;
            float ri = rsqrtf(di[r]);
            #pragma unroll
            for (int c = 0; c < 3; ++c) {
                int j = tx + 32 * c;
                float v = (i == j) ? 0.f : acc[r][c] * ri * rsj[c];
                ob[(size_t)i * An + j] = v;
            }
        }
    };

    // --- warm-up: full window sum for t0 ---
    for (int s = sbase; s <= t0; ++s) accum(s - sbase, 1.0f);
    emit(t0);

    // --- slide: W(t) = W(t-1) + g(t) - g(t-WIN) ---
    for (int t = t0 + 1; t <= t1; ++t) {
        accum(t - sbase, 1.0f);
        if (t >= WIN) accum(t - WIN - sbase, -1.0f);
        emit(t);
    }
}

extern "C" void kernel_launch(void* const* d_in, const int* in_sizes, int n_in,
                              void* d_out, int out_size, void* d_ws, size_t ws_size,
                              hipStream_t stream) {
    const float* in = (const float*)d_in[0];
    float* out = (float*)d_out;
    float* sums    = (float*)d_ws;                  // 1536 floats
    float* partial = (float*)d_ws + Bn * AV;        // 24576 floats

    partial_kernel<<<Bn * NCH, 192, 0, stream>>>(in, partial);
    reduce_kernel<<<(Bn * AV + 255) / 256, 256, 0, stream>>>(partial, sums);
    corr_kernel<<<Bn * CHUNKS_PER_B, 256, 0, stream>>>(in, sums, out);
}

// Round 3
// 40.919 us; speedup vs baseline: 1.6924x; 1.0325x over previous
//
#include <hip/hip_runtime.h>

// inputs (8, 512, 96, 2) f32, WIN=10. Output (8, 511, 96, 96) f32 = 150.7 MB.
constexpr int WIN = 10;
constexpr int Bn  = 8;
constexpr int Sn  = 512;
constexpr int An  = 96;
constexpr int Tn  = Sn - 1;         // 511 output time steps
constexpr int AV  = An * 2;         // 192

constexpr int SCHUNK = 32;          // s-rows per partial-sum block
constexpr int NCH    = Sn / SCHUNK; // 16
constexpr int CH     = 8;           // t-outputs per corr block
constexpr int CHUNKS_PER_B = (Tn + CH - 1) / CH;   // 64
constexpr int MAXROWS = CH + WIN - 1;              // 17 staged s-rows
constexpr int ISPLIT  = 2;                         // i-rows split across blocks
constexpr int RPT     = (An / ISPLIT) / 8;         // 6 rows per thread

// ---- mean pass, stage 1: partial sums over 32-s chunks (coalesced) ----
__global__ __launch_bounds__(192)
void partial_kernel(const float* __restrict__ in, float* __restrict__ partial) {
    const int blk = blockIdx.x;             // b * NCH + c
    const int b   = blk / NCH;
    const int c   = blk - b * NCH;
    const int av  = threadIdx.x;            // 0..191
    const float* p = in + ((size_t)(b * Sn + c * SCHUNK)) * AV + av;
    float acc = 0.f;
    #pragma unroll
    for (int s = 0; s < SCHUNK; ++s) acc += p[(size_t)s * AV];
    partial[(size_t)blk * AV + av] = acc;
}

// ---- mean pass, stage 2: reduce 16 partials -> per-(b,av) sum ----
__global__ __launch_bounds__(256)
void reduce_kernel(const float* __restrict__ partial, float* __restrict__ sums) {
    int idx = blockIdx.x * blockDim.x + threadIdx.x;
    if (idx >= Bn * AV) return;
    int b  = idx / AV;
    int av = idx - b * AV;
    float acc = 0.f;
    #pragma unroll
    for (int c = 0; c < NCH; ++c) acc += partial[(size_t)(b * NCH + c) * AV + av];
    sums[idx] = acc;   // raw sum; corr scales by 1/Sn
}

// ---- corr: one block per (b, 8-t chunk, i-half); sliding-window updates ----
__global__ __launch_bounds__(256)
void corr_kernel(const float* __restrict__ in, const float* __restrict__ sums,
                 float* __restrict__ out) {
    __shared__ float xw[MAXROWS * AV];   // centered rows, 12.75 KB

    const int bid   = blockIdx.x;
    const int b     = bid / (CHUNKS_PER_B * ISPLIT);
    const int rem   = bid - b * (CHUNKS_PER_B * ISPLIT);
    const int chunk = rem >> 1;          // ISPLIT == 2
    const int half  = rem & 1;
    const int i0    = half * (An / ISPLIT);

    const int t0 = chunk * CH;
    const int t1 = min(t0 + CH - 1, Tn - 1);
    int sbase = t0 - (WIN - 1); if (sbase < 0) sbase = 0;
    const int nrows = t1 - sbase + 1;    // <= 17

    const int tid = threadIdx.x;

    // --- stage rows [sbase..t1], centered, float4-vectorized ---
    {
        const float4* src = reinterpret_cast<const float4*>(
            in + ((size_t)(b * Sn + sbase)) * AV);
        const float4* mb = reinterpret_cast<const float4*>(sums + b * AV);
        float4* dst = reinterpret_cast<float4*>(xw);
        const int tot4 = nrows * (AV / 4);
        constexpr float invS = 1.0f / Sn;
        for (int idx = tid; idx < tot4; idx += 256) {
            int av4 = idx % (AV / 4);
            float4 v = src[idx], m = mb[av4];
            v.x -= m.x * invS; v.y -= m.y * invS;
            v.z -= m.z * invS; v.w -= m.w * invS;
            dst[idx] = v;
        }
    }
    __syncthreads();

    const int tx = tid & 31;   // j = tx + 32c
    const int ty = tid >> 5;   // i = i0 + ty + 8r

    float acc[RPT][3];
    float di[RPT], dj[3];
    #pragma unroll
    for (int r = 0; r < RPT; ++r) {
        di[r] = 0.f;
        #pragma unroll
        for (int c = 0; c < 3; ++c) acc[r][c] = 0.f;
    }
    #pragma unroll
    for (int c = 0; c < 3; ++c) dj[c] = 0.f;

#define ACCUM(ls, OP)                                                       \
    {                                                                       \
        const float* xs = &xw[(ls) * AV];                                   \
        float2 xj[3];                                                       \
        _Pragma("unroll")                                                   \
        for (int c = 0; c < 3; ++c) {                                       \
            xj[c] = *reinterpret_cast<const float2*>(&xs[(tx + 32 * c) * 2]);\
            dj[c] OP (xj[c].x * xj[c].x + xj[c].y * xj[c].y);               \
        }                                                                   \
        _Pragma("unroll")                                                   \
        for (int r = 0; r < RPT; ++r) {                                     \
            float2 xi = *reinterpret_cast<const float2*>(                   \
                &xs[(i0 + ty + 8 * r) * 2]);                                \
            di[r] OP (xi.x * xi.x + xi.y * xi.y);                           \
            _Pragma("unroll")                                               \
            for (int c = 0; c < 3; ++c)                                     \
                acc[r][c] OP (xi.x * xj[c].x + xi.y * xj[c].y);             \
        }                                                                   \
    }

    // normalize + mask + store one t
    auto emit = [&](int t) {
        float rsj[3];
        #pragma unroll
        for (int c = 0; c < 3; ++c) rsj[c] = rsqrtf(dj[c]);
        float* ob = out + (size_t)(b * Tn + t) * (An * An);
        #pragma unroll
        for (int r = 0; r < RPT; ++r) {
            int i = i0 + ty + 8 * r;
            float ri = rsqrtf(di[r]);
            #pragma unroll
            for (int c = 0; c < 3; ++c) {
                int j = tx + 32 * c;
                float v = (i == j) ? 0.f : acc[r][c] * ri * rsj[c];
                ob[(size_t)i * An + j] = v;
            }
        }
    };

    // --- warm-up: full window sum for t0 ---
    for (int s = sbase; s <= t0; ++s) ACCUM(s - sbase, +=);
    emit(t0);

    // --- slide: W(t) = W(t-1) + g(t) - g(t-WIN) ---
    for (int t = t0 + 1; t <= t1; ++t) {
        ACCUM(t - sbase, +=);
        if (t >= WIN) ACCUM(t - WIN - sbase, -=);
        emit(t);
    }
#undef ACCUM
}

extern "C" void kernel_launch(void* const* d_in, const int* in_sizes, int n_in,
                              void* d_out, int out_size, void* d_ws, size_t ws_size,
                              hipStream_t stream) {
    const float* in = (const float*)d_in[0];
    float* out = (float*)d_out;
    float* sums    = (float*)d_ws;                  // 1536 floats
    float* partial = (float*)d_ws + Bn * AV;        // 24576 floats

    partial_kernel<<<Bn * NCH, 192, 0, stream>>>(in, partial);
    reduce_kernel<<<(Bn * AV + 255) / 256, 256, 0, stream>>>(partial, sums);
    corr_kernel<<<Bn * CHUNKS_PER_B * ISPLIT, 256, 0, stream>>>(in, sums, out);
}

// Round 4
// 40.577 us; speedup vs baseline: 1.7067x; 1.0084x over previous
//
#include <hip/hip_runtime.h>

// inputs (8, 512, 96, 2) f32, WIN=10. Output (8, 511, 96, 96) f32 = 150.7 MB.
constexpr int WIN = 10;
constexpr int Bn  = 8;
constexpr int Sn  = 512;
constexpr int An  = 96;
constexpr int Tn  = Sn - 1;          // 511
constexpr int AV  = An * 2;          // 192

constexpr int SCHUNK = 32;           // s-rows per partial-sum block
constexpr int NCH    = Sn / SCHUNK;  // 16
constexpr int CH     = 16;           // t-outputs per corr block
constexpr int CHUNKS_PER_B = (Tn + CH - 1) / CH;   // 32
constexpr int MAXROWS = CH + WIN - 1;              // 25 staged s-rows
constexpr int ISPLIT  = 4;                         // i-rows split across blocks
constexpr int ROWS    = An / ISPLIT;               // 24 rows per block
constexpr int NTHR    = 192;
constexpr int TXN     = 24;          // float4-column index 0..23  (j = 4*tx+c)
constexpr int TYN     = NTHR / TXN;  // 8
constexpr int RPT     = ROWS / TYN;  // 3 rows per thread

// ---- mean pass: partial sums over 32-s chunks (coalesced) ----
__global__ __launch_bounds__(192)
void partial_kernel(const float* __restrict__ in, float* __restrict__ partial) {
    const int blk = blockIdx.x;              // b * NCH + c
    const int b   = blk / NCH;
    const int c   = blk - b * NCH;
    const int av  = threadIdx.x;             // 0..191
    const float* p = in + ((size_t)(b * Sn + c * SCHUNK)) * AV + av;
    float acc = 0.f;
    #pragma unroll
    for (int s = 0; s < SCHUNK; ++s) acc += p[(size_t)s * AV];
    partial[(size_t)blk * AV + av] = acc;
}

// ---- corr: one block per (b, 16-t chunk, i-quarter) ----
__global__ __launch_bounds__(192)
void corr_kernel(const float* __restrict__ in, const float* __restrict__ partial,
                 float* __restrict__ out) {
    __shared__ __align__(16) float xw[MAXROWS * AV];  // centered rows, 18.75 KB
    __shared__ __align__(16) float smu[AV];           // per-(a,v) mean

    const int bid     = blockIdx.x;
    const int b       = bid / (CHUNKS_PER_B * ISPLIT);
    const int rem     = bid - b * (CHUNKS_PER_B * ISPLIT);
    const int chunk   = rem >> 2;            // ISPLIT == 4
    const int quarter = rem & 3;
    const int i0      = quarter * ROWS;

    const int t0 = chunk * CH;
    const int t1 = min(t0 + CH - 1, Tn - 1);
    int sbase = t0 - (WIN - 1); if (sbase < 0) sbase = 0;
    const int nrows = t1 - sbase + 1;        // <= 25

    const int tid = threadIdx.x;

    // --- reduce 16 partials -> mean, in LDS (replaces reduce_kernel) ---
    {
        const float* pp = partial + (size_t)b * NCH * AV + tid;
        float acc = 0.f;
        #pragma unroll
        for (int c = 0; c < NCH; ++c) acc += pp[(size_t)c * AV];
        smu[tid] = acc * (1.0f / Sn);
    }
    __syncthreads();

    // --- stage rows [sbase..t1], centered, float4-vectorized ---
    {
        const float4* src = reinterpret_cast<const float4*>(
            in + ((size_t)(b * Sn + sbase)) * AV);
        const float4* mb4 = reinterpret_cast<const float4*>(smu);
        float4* dst = reinterpret_cast<float4*>(xw);
        const int tot4 = nrows * (AV / 4);
        for (int idx = tid; idx < tot4; idx += NTHR) {
            int av4 = idx % (AV / 4);
            float4 v = src[idx], m = mb4[av4];
            v.x -= m.x; v.y -= m.y; v.z -= m.z; v.w -= m.w;
            dst[idx] = v;
        }
    }
    __syncthreads();

    const int tx = tid % TXN;   // float4 col: j = 4*tx + c
    const int ty = tid / TXN;   // row group: i = i0 + ty + 8*r

    float acc[RPT][4];
    float di[RPT], dj[4];
    #pragma unroll
    for (int r = 0; r < RPT; ++r) {
        di[r] = 0.f;
        #pragma unroll
        for (int c = 0; c < 4; ++c) acc[r][c] = 0.f;
    }
    #pragma unroll
    for (int c = 0; c < 4; ++c) dj[c] = 0.f;

#define ACCUM(ls, OP)                                                        \
    {                                                                        \
        const float* xs = &xw[(ls) * AV];                                    \
        float4 xj0 = *reinterpret_cast<const float4*>(&xs[8 * tx]);          \
        float4 xj1 = *reinterpret_cast<const float4*>(&xs[8 * tx + 4]);      \
        dj[0] OP (xj0.x * xj0.x + xj0.y * xj0.y);                            \
        dj[1] OP (xj0.z * xj0.z + xj0.w * xj0.w);                            \
        dj[2] OP (xj1.x * xj1.x + xj1.y * xj1.y);                            \
        dj[3] OP (xj1.z * xj1.z + xj1.w * xj1.w);                            \
        _Pragma("unroll")                                                    \
        for (int r = 0; r < RPT; ++r) {                                      \
            float2 xi = *reinterpret_cast<const float2*>(                    \
                &xs[(i0 + ty + 8 * r) * 2]);                                 \
            di[r] OP (xi.x * xi.x + xi.y * xi.y);                            \
            acc[r][0] OP (xi.x * xj0.x + xi.y * xj0.y);                      \
            acc[r][1] OP (xi.x * xj0.z + xi.y * xj0.w);                      \
            acc[r][2] OP (xi.x * xj1.x + xi.y * xj1.y);                      \
            acc[r][3] OP (xi.x * xj1.z + xi.y * xj1.w);                      \
        }                                                                    \
    }

    // normalize + mask + store one t (one float4 store per r, 1KB/wave-instr)
    auto emit = [&](int t) {
        float rsj[4];
        #pragma unroll
        for (int c = 0; c < 4; ++c) rsj[c] = rsqrtf(dj[c]);
        float* ob = out + (size_t)(b * Tn + t) * (An * An);
        #pragma unroll
        for (int r = 0; r < RPT; ++r) {
            int i = i0 + ty + 8 * r;
            float ri = rsqrtf(di[r]);
            float4 v;
            v.x = (i == 4 * tx + 0) ? 0.f : acc[r][0] * ri * rsj[0];
            v.y = (i == 4 * tx + 1) ? 0.f : acc[r][1] * ri * rsj[1];
            v.z = (i == 4 * tx + 2) ? 0.f : acc[r][2] * ri * rsj[2];
            v.w = (i == 4 * tx + 3) ? 0.f : acc[r][3] * ri * rsj[3];
            *reinterpret_cast<float4*>(&ob[(size_t)i * An + 4 * tx]) = v;
        }
    };

    // --- warm-up: full window sum for t0 ---
    for (int s = sbase; s <= t0; ++s) ACCUM(s - sbase, +=);
    emit(t0);

    // --- slide: W(t) = W(t-1) + g(t) - g(t-WIN) ---
    for (int t = t0 + 1; t <= t1; ++t) {
        ACCUM(t - sbase, +=);
        if (t >= WIN) ACCUM(t - WIN - sbase, -=);
        emit(t);
    }
#undef ACCUM
}

extern "C" void kernel_launch(void* const* d_in, const int* in_sizes, int n_in,
                              void* d_out, int out_size, void* d_ws, size_t ws_size,
                              hipStream_t stream) {
    const float* in = (const float*)d_in[0];
    float* out = (float*)d_out;
    float* partial = (float*)d_ws;    // Bn*NCH*AV = 24576 floats

    partial_kernel<<<Bn * NCH, 192, 0, stream>>>(in, partial);
    corr_kernel<<<Bn * CHUNKS_PER_B * ISPLIT, NTHR, 0, stream>>>(in, partial, out);
}